// Round 1
// baseline (94.379 us; speedup 1.0000x reference)
//
#include <hip/hip_runtime.h>
#include <math.h>

#define B_DIM 256
#define M_DIM 256
#define C_DIM 1024
#define C4 256               // C/4 float4 per row
#define Z_OFF   0
#define UM_OFF  (B_DIM * C_DIM)                         // 262144 floats
#define KL_OFF  (UM_OFF + B_DIM * M_DIM * C_DIM)        // 67371008 floats
#define SCALE   0.03125f     // 1/sqrt(1024)

// Kernel 1: per-batch sims, argmax, softmax, z_read, kl_div. One block per b.
__global__ __launch_bounds__(256) void tm_k1(const float* __restrict__ x,
                                             const float* __restrict__ mem,
                                             float* __restrict__ out,
                                             int* __restrict__ idx_ws) {
    const int b = blockIdx.x;
    const int t = threadIdx.x;
    const int lane = t & 63;
    const int wv = t >> 6;   // 0..3

    __shared__ float4 s_x4[C4];     // input row
    __shared__ float  s_sims[M_DIM];
    __shared__ float  s_attn[M_DIM];
    __shared__ float  s_rv[256];
    __shared__ int    s_ri[256];
    __shared__ float  s_red[256];

    const float4* x4   = (const float4*)(x + (size_t)b * C_DIM);
    const float4* mem4 = (const float4*)mem;

    // ---- load x row, partial ||x||^2 ----
    float4 xt = x4[t];
    s_x4[t] = xt;
    s_red[t] = xt.x * xt.x + xt.y * xt.y + xt.z * xt.z + xt.w * xt.w;
    __syncthreads();
    for (int off = 128; off > 0; off >>= 1) {
        if (t < off) s_red[t] += s_red[t + off];
        __syncthreads();
    }
    const float n2 = s_red[0];

    // ---- sims: each wave handles m = wv, wv+4, ... (64 rows/wave) ----
    // register copy of x fragment for this lane
    float4 xr0 = s_x4[lane];
    float4 xr1 = s_x4[lane + 64];
    float4 xr2 = s_x4[lane + 128];
    float4 xr3 = s_x4[lane + 192];
    for (int m = wv; m < M_DIM; m += 4) {
        const float4* mr = mem4 + (size_t)m * C4;
        float4 a0 = mr[lane];
        float4 a1 = mr[lane + 64];
        float4 a2 = mr[lane + 128];
        float4 a3 = mr[lane + 192];
        float acc = a0.x * xr0.x + a0.y * xr0.y + a0.z * xr0.z + a0.w * xr0.w
                  + a1.x * xr1.x + a1.y * xr1.y + a1.z * xr1.z + a1.w * xr1.w
                  + a2.x * xr2.x + a2.y * xr2.y + a2.z * xr2.z + a2.w * xr2.w
                  + a3.x * xr3.x + a3.y * xr3.y + a3.z * xr3.z + a3.w * xr3.w;
        #pragma unroll
        for (int off = 32; off > 0; off >>= 1)
            acc += __shfl_down(acc, off, 64);
        if (lane == 0) s_sims[m] = acc;
    }
    __syncthreads();

    // ---- argmax over m (first-max tie-break, like np.argmax) ----
    s_rv[t] = s_sims[t];
    s_ri[t] = t;
    __syncthreads();
    for (int off = 128; off > 0; off >>= 1) {
        if (t < off) {
            float v2 = s_rv[t + off];
            int   i2 = s_ri[t + off];
            if (v2 > s_rv[t] || (v2 == s_rv[t] && i2 < s_ri[t])) {
                s_rv[t] = v2;
                s_ri[t] = i2;
            }
        }
        __syncthreads();
    }
    const int idx = s_ri[0];
    const float sim_idx = s_sims[idx];

    // ---- scores & softmax (thread t owns slot m = t) ----
    float sc = (t == idx) ? (0.9f * sim_idx + 0.1f * n2) * SCALE
                          : s_sims[t] * SCALE;
    s_red[t] = sc;
    __syncthreads();
    for (int off = 128; off > 0; off >>= 1) {
        if (t < off) s_red[t] = fmaxf(s_red[t], s_red[t + off]);
        __syncthreads();
    }
    const float mx = s_red[0];
    __syncthreads();
    float e = expf(sc - mx);
    s_red[t] = e;
    __syncthreads();
    for (int off = 128; off > 0; off >>= 1) {
        if (t < off) s_red[t] += s_red[t + off];
        __syncthreads();
    }
    const float esum = s_red[0];
    s_attn[t] = e / esum;
    __syncthreads();

    // ---- dkl_write pieces & z_read ----
    float4 sl = mem4[(size_t)idx * C4 + t];
    float4 d;
    d.x = xt.x - sl.x; d.y = xt.y - sl.y; d.z = xt.z - sl.z; d.w = xt.w - sl.w;
    float dwp = d.x * d.x + d.y * d.y + d.z * d.z + d.w * d.w;

    float4 z = make_float4(0.f, 0.f, 0.f, 0.f);
    for (int m = 0; m < M_DIM; ++m) {
        float a = s_attn[m];
        float4 v = mem4[(size_t)m * C4 + t];
        z.x = fmaf(a, v.x, z.x);
        z.y = fmaf(a, v.y, z.y);
        z.z = fmaf(a, v.z, z.z);
        z.w = fmaf(a, v.w, z.w);
    }
    const float aidx = s_attn[idx] * 0.1f;
    z.x = fmaf(aidx, d.x, z.x);
    z.y = fmaf(aidx, d.y, z.y);
    z.z = fmaf(aidx, d.z, z.z);
    z.w = fmaf(aidx, d.w, z.w);

    float4 dz;
    dz.x = z.x - xt.x; dz.y = z.y - xt.y; dz.z = z.z - xt.z; dz.w = z.w - xt.w;
    float drp = dz.x * dz.x + dz.y * dz.y + dz.z * dz.z + dz.w * dz.w;

    // ---- reduce the two KL partials ----
    __syncthreads();
    s_red[t] = dwp;
    __syncthreads();
    for (int off = 128; off > 0; off >>= 1) {
        if (t < off) s_red[t] += s_red[t + off];
        __syncthreads();
    }
    const float dw = s_red[0];
    __syncthreads();
    s_red[t] = drp;
    __syncthreads();
    for (int off = 128; off > 0; off >>= 1) {
        if (t < off) s_red[t] += s_red[t + off];
        __syncthreads();
    }
    const float dr = s_red[0];

    if (t == 0) {
        out[KL_OFF + b] = 0.5f * (dw + dr);
        idx_ws[b] = idx;
    }

    // ---- write z_read row ----
    ((float4*)(out + Z_OFF))[(size_t)b * C4 + t] = z;
}

// Kernel 2: stream updated_memory. One block per (m, b) row.
__global__ __launch_bounds__(256) void tm_k2(const float* __restrict__ x,
                                             const float* __restrict__ mem,
                                             const int* __restrict__ idx_ws,
                                             float* __restrict__ out_um) {
    const int m = blockIdx.x;
    const int b = blockIdx.y;
    const int t = threadIdx.x;

    const float4* mem4 = (const float4*)mem;
    float4 v = mem4[(size_t)m * C4 + t];
    if (m == idx_ws[b]) {
        const float4* x4 = (const float4*)(x + (size_t)b * C_DIM);
        float4 xv = x4[t];
        v.x = 0.9f * v.x + 0.1f * xv.x;
        v.y = 0.9f * v.y + 0.1f * xv.y;
        v.z = 0.9f * v.z + 0.1f * xv.z;
        v.w = 0.9f * v.w + 0.1f * xv.w;
    }
    ((float4*)out_um)[((size_t)b * M_DIM + m) * C4 + t] = v;
}

extern "C" void kernel_launch(void* const* d_in, const int* in_sizes, int n_in,
                              void* d_out, int out_size, void* d_ws, size_t ws_size,
                              hipStream_t stream) {
    const float* x   = (const float*)d_in[0];   // input_encoded [B, C]
    const float* mem = (const float*)d_in[1];   // memory_mean  [M, C]
    float* out = (float*)d_out;
    int* idx_ws = (int*)d_ws;

    tm_k1<<<dim3(B_DIM), dim3(256), 0, stream>>>(x, mem, out, idx_ws);

    dim3 g2(M_DIM, B_DIM);
    tm_k2<<<g2, dim3(256), 0, stream>>>(x, mem, idx_ws, out + UM_OFF);
}

// Round 3
// 70.954 us; speedup vs baseline: 1.3301x; 1.3301x over previous
//
#include <hip/hip_runtime.h>
#include <math.h>

#define B_DIM 256
#define M_DIM 256
#define C_DIM 1024
#define C4 256               // C/4 float4 per row
#define Z_OFF   0
#define UM_OFF  (B_DIM * C_DIM)                         // 262144 floats
#define KL_OFF  (UM_OFF + B_DIM * M_DIM * C_DIM)        // 67371008 floats
#define SCALE   0.03125f     // 1/sqrt(1024)

typedef float nfloat4 __attribute__((ext_vector_type(4)));  // native vec for nontemporal

// block-wide sum over 8 waves; returns result in ALL threads
__device__ __forceinline__ float block_sum8(float v, float* s_w, int lane, int wv) {
    #pragma unroll
    for (int off = 32; off; off >>= 1) v += __shfl_xor(v, off, 64);
    if (lane == 0) s_w[wv] = v;
    __syncthreads();
    float r = s_w[0] + s_w[1] + s_w[2] + s_w[3]
            + s_w[4] + s_w[5] + s_w[6] + s_w[7];
    __syncthreads();
    return r;
}

__device__ __forceinline__ float block_max8(float v, float* s_w, int lane, int wv) {
    #pragma unroll
    for (int off = 32; off; off >>= 1) v = fmaxf(v, __shfl_xor(v, off, 64));
    if (lane == 0) s_w[wv] = v;
    __syncthreads();
    float r = fmaxf(fmaxf(fmaxf(s_w[0], s_w[1]), fmaxf(s_w[2], s_w[3])),
                    fmaxf(fmaxf(s_w[4], s_w[5]), fmaxf(s_w[6], s_w[7])));
    __syncthreads();
    return r;
}

// One block per batch row b. 512 threads = 8 waves.
__global__ __launch_bounds__(512) void tm_fused(const float* __restrict__ x,
                                                const float* __restrict__ mem,
                                                float* __restrict__ out) {
    const int b = blockIdx.x;
    const int t = threadIdx.x;
    const int lane = t & 63;
    const int wv = t >> 6;      // 0..7

    __shared__ float4 s_x4[C4];     // 4 KB
    __shared__ float  s_sims[M_DIM];
    __shared__ float  s_attn[M_DIM];
    __shared__ float4 s_z4[C4];     // 4 KB
    __shared__ float  s_w[8];
    __shared__ float  s_av[4];
    __shared__ int    s_ai[4];
    __shared__ int    s_idx;
    __shared__ float  s_vidx;

    const float4* mem4 = (const float4*)mem;
    const float4* x4row = (const float4*)(x + (size_t)b * C_DIM);

    // ---- phase 1: load x row, ||x||^2 ----
    float4 xt = make_float4(0.f, 0.f, 0.f, 0.f);
    float p = 0.f;
    if (t < C4) {
        xt = x4row[t];
        s_x4[t] = xt;
        p = xt.x * xt.x + xt.y * xt.y + xt.z * xt.z + xt.w * xt.w;
    }
    const float n2 = block_sum8(p, s_w, lane, wv);  // internal barrier publishes s_x4

    // ---- phase 2: sims (each wave owns m = wv, wv+8, ...; 32 rows/wave) ----
    float4 xr0 = s_x4[lane];
    float4 xr1 = s_x4[lane + 64];
    float4 xr2 = s_x4[lane + 128];
    float4 xr3 = s_x4[lane + 192];
    for (int i = 0; i < 32; ++i) {
        const int m = (i << 3) | wv;
        const float4* mr = mem4 + (size_t)m * C4;
        float4 a0 = mr[lane];
        float4 a1 = mr[lane + 64];
        float4 a2 = mr[lane + 128];
        float4 a3 = mr[lane + 192];
        float acc = a0.x * xr0.x + a0.y * xr0.y + a0.z * xr0.z + a0.w * xr0.w
                  + a1.x * xr1.x + a1.y * xr1.y + a1.z * xr1.z + a1.w * xr1.w
                  + a2.x * xr2.x + a2.y * xr2.y + a2.z * xr2.z + a2.w * xr2.w
                  + a3.x * xr3.x + a3.y * xr3.y + a3.z * xr3.z + a3.w * xr3.w;
        #pragma unroll
        for (int off = 32; off; off >>= 1) acc += __shfl_xor(acc, off, 64);
        if (lane == 0) s_sims[m] = acc;
    }
    __syncthreads();

    // ---- phase 3: argmax (first-max tie-break, like np.argmax) ----
    float av = -INFINITY;
    int   ai = 0x7fffffff;
    if (t < M_DIM) { av = s_sims[t]; ai = t; }
    #pragma unroll
    for (int off = 32; off; off >>= 1) {
        float ov = __shfl_xor(av, off, 64);
        int   oi = __shfl_xor(ai, off, 64);
        if (ov > av || (ov == av && oi < ai)) { av = ov; ai = oi; }
    }
    if (lane == 0 && wv < 4) { s_av[wv] = av; s_ai[wv] = ai; }
    __syncthreads();
    if (t == 0) {
        float bv = s_av[0]; int bi = s_ai[0];
        #pragma unroll
        for (int w = 1; w < 4; ++w) {
            float v2 = s_av[w]; int i2 = s_ai[w];
            if (v2 > bv || (v2 == bv && i2 < bi)) { bv = v2; bi = i2; }
        }
        s_idx = bi; s_vidx = bv;
    }
    __syncthreads();
    const int idx = s_idx;
    const float sim_idx = s_vidx;

    // ---- phase 4: scores + softmax (thread t owns slot m=t, t<256) ----
    float sc = -INFINITY;
    if (t < M_DIM)
        sc = (t == idx) ? (0.9f * sim_idx + 0.1f * n2) * SCALE
                        : s_sims[t] * SCALE;
    const float mx = block_max8(sc, s_w, lane, wv);
    float e = (t < M_DIM) ? expf(sc - mx) : 0.f;
    const float esum = block_sum8(e, s_w, lane, wv);
    if (t < M_DIM) s_attn[t] = e / esum;

    // ---- phase 5: dkl_write = 0.5*||x - mem[idx]||^2 ----
    float dwp = 0.f;
    if (t < C4) {
        float4 sl = mem4[(size_t)idx * C4 + t];
        float d0 = xt.x - sl.x, d1 = xt.y - sl.y, d2 = xt.z - sl.z, d3 = xt.w - sl.w;
        dwp = d0 * d0 + d1 * d1 + d2 * d2 + d3 * d3;
    }
    const float dw = block_sum8(dwp, s_w, lane, wv);  // barrier also publishes s_attn

    // ---- phase 6: z_read + updated_memory stream (halves split over m) ----
    const int tc = t & 255;              // column chunk (float4 id)
    const int mbase = (t >> 8) << 7;     // 0 for waves 0-3, 128 for waves 4-7
    const float4 xc = s_x4[tc];
    float4 z = make_float4(0.f, 0.f, 0.f, 0.f);
    nfloat4* um4 = (nfloat4*)((float4*)(out + UM_OFF) + (size_t)b * M_DIM * C4 + tc);
    for (int i = 0; i < 128; ++i) {
        const int m = mbase + i;
        float4 v = mem4[(size_t)m * C4 + tc];
        if (m == idx) {      // wave-uniform branch
            v.x = 0.9f * v.x + 0.1f * xc.x;
            v.y = 0.9f * v.y + 0.1f * xc.y;
            v.z = 0.9f * v.z + 0.1f * xc.z;
            v.w = 0.9f * v.w + 0.1f * xc.w;
        }
        const float a = s_attn[m];
        z.x = fmaf(a, v.x, z.x);
        z.y = fmaf(a, v.y, z.y);
        z.z = fmaf(a, v.z, z.z);
        z.w = fmaf(a, v.w, z.w);
        nfloat4 nv = { v.x, v.y, v.z, v.w };
        __builtin_nontemporal_store(nv, um4 + (size_t)m * C4);
    }

    // combine the two m-halves
    if (t >= 256) s_z4[tc] = z;
    __syncthreads();
    float drp = 0.f;
    if (t < 256) {
        float4 zo = s_z4[tc];
        z.x += zo.x; z.y += zo.y; z.z += zo.z; z.w += zo.w;
        float d0 = z.x - xc.x, d1 = z.y - xc.y, d2 = z.z - xc.z, d3 = z.w - xc.w;
        drp = d0 * d0 + d1 * d1 + d2 * d2 + d3 * d3;
        ((float4*)(out + Z_OFF))[(size_t)b * C4 + t] = z;
    }
    const float dr = block_sum8(drp, s_w, lane, wv);

    if (t == 0) out[KL_OFF + b] = 0.5f * (dw + dr);
}

extern "C" void kernel_launch(void* const* d_in, const int* in_sizes, int n_in,
                              void* d_out, int out_size, void* d_ws, size_t ws_size,
                              hipStream_t stream) {
    const float* x   = (const float*)d_in[0];   // input_encoded [B, C]
    const float* mem = (const float*)d_in[1];   // memory_mean  [M, C]
    float* out = (float*)d_out;

    tm_fused<<<dim3(B_DIM), dim3(512), 0, stream>>>(x, mem, out);
}

// Round 4
// 67.826 us; speedup vs baseline: 1.3915x; 1.0461x over previous
//
#include <hip/hip_runtime.h>
#include <math.h>

#define B_DIM 256
#define M_DIM 256
#define C_DIM 1024
#define C4 256               // C/4 float4 per row
#define Z_OFF   0
#define UM_OFF  (B_DIM * C_DIM)                         // 262144 floats
#define KL_OFF  (UM_OFF + B_DIM * M_DIM * C_DIM)        // 67371008 floats
#define SCALE   0.03125f     // 1/sqrt(1024)

typedef float nfloat4 __attribute__((ext_vector_type(4)));  // native vec for nontemporal

// block-wide sum over 16 waves; returns result in ALL threads
__device__ __forceinline__ float block_sum16(float v, float* s_w, int lane, int wv) {
    #pragma unroll
    for (int off = 32; off; off >>= 1) v += __shfl_xor(v, off, 64);
    if (lane == 0) s_w[wv] = v;
    __syncthreads();
    float r = 0.f;
    #pragma unroll
    for (int w = 0; w < 16; ++w) r += s_w[w];
    __syncthreads();
    return r;
}

__device__ __forceinline__ float block_max16(float v, float* s_w, int lane, int wv) {
    #pragma unroll
    for (int off = 32; off; off >>= 1) v = fmaxf(v, __shfl_xor(v, off, 64));
    if (lane == 0) s_w[wv] = v;
    __syncthreads();
    float r = s_w[0];
    #pragma unroll
    for (int w = 1; w < 16; ++w) r = fmaxf(r, s_w[w]);
    __syncthreads();
    return r;
}

// One block per batch row b. 1024 threads = 16 waves (4 waves/SIMD).
__global__ __launch_bounds__(1024) void tm_fused(const float* __restrict__ x,
                                                 const float* __restrict__ mem,
                                                 float* __restrict__ out) {
    const int b = blockIdx.x;
    const int t = threadIdx.x;
    const int lane = t & 63;
    const int wv = t >> 6;      // 0..15

    __shared__ float4 s_x4[C4];        // 4 KB  input row
    __shared__ float4 s_d4[C4];        // 4 KB  x - mem[idx]
    __shared__ float4 s_z4[3][C4];     // 12 KB z partials from groups 1..3
    __shared__ float  s_sims[M_DIM];
    __shared__ float  s_attn[M_DIM];
    __shared__ float  s_w[16];
    __shared__ float  s_av[4];
    __shared__ int    s_ai[4];
    __shared__ int    s_idx;
    __shared__ float  s_vidx;

    const float4* mem4 = (const float4*)mem;

    // ---- phase 1: load x row, ||x||^2 ----
    float4 xt = make_float4(0.f, 0.f, 0.f, 0.f);
    float p = 0.f;
    if (t < C4) {
        xt = ((const float4*)(x + (size_t)b * C_DIM))[t];
        s_x4[t] = xt;
        p = xt.x * xt.x + xt.y * xt.y + xt.z * xt.z + xt.w * xt.w;
    }
    const float n2 = block_sum16(p, s_w, lane, wv);  // internal barrier publishes s_x4

    // ---- phase 2: sims (16 waves, 16 rows/wave) ----
    float4 xr0 = s_x4[lane];
    float4 xr1 = s_x4[lane + 64];
    float4 xr2 = s_x4[lane + 128];
    float4 xr3 = s_x4[lane + 192];
    for (int i = 0; i < 16; ++i) {
        const int m = (i << 4) | wv;
        const float4* mr = mem4 + (size_t)m * C4;
        float4 a0 = mr[lane];
        float4 a1 = mr[lane + 64];
        float4 a2 = mr[lane + 128];
        float4 a3 = mr[lane + 192];
        float acc = a0.x * xr0.x + a0.y * xr0.y + a0.z * xr0.z + a0.w * xr0.w
                  + a1.x * xr1.x + a1.y * xr1.y + a1.z * xr1.z + a1.w * xr1.w
                  + a2.x * xr2.x + a2.y * xr2.y + a2.z * xr2.z + a2.w * xr2.w
                  + a3.x * xr3.x + a3.y * xr3.y + a3.z * xr3.z + a3.w * xr3.w;
        #pragma unroll
        for (int off = 32; off; off >>= 1) acc += __shfl_xor(acc, off, 64);
        if (lane == 0) s_sims[m] = acc;
    }
    __syncthreads();

    // ---- phase 3: argmax (first-max tie-break) ----
    float av = -INFINITY;
    int   ai = 0x7fffffff;
    if (t < M_DIM) { av = s_sims[t]; ai = t; }
    if (wv < 4) {
        #pragma unroll
        for (int off = 32; off; off >>= 1) {
            float ov = __shfl_xor(av, off, 64);
            int   oi = __shfl_xor(ai, off, 64);
            if (ov > av || (ov == av && oi < ai)) { av = ov; ai = oi; }
        }
        if (lane == 0) { s_av[wv] = av; s_ai[wv] = ai; }
    }
    __syncthreads();
    if (t == 0) {
        float bv = s_av[0]; int bi = s_ai[0];
        #pragma unroll
        for (int w = 1; w < 4; ++w) {
            float v2 = s_av[w]; int i2 = s_ai[w];
            if (v2 > bv || (v2 == bv && i2 < bi)) { bv = v2; bi = i2; }
        }
        s_idx = bi; s_vidx = bv;
    }
    __syncthreads();
    const int idx = s_idx;
    const float sim_idx = s_vidx;

    // ---- phase 4: scores + softmax (thread t owns slot m=t, t<256) ----
    float sc = -INFINITY;
    if (t < M_DIM)
        sc = (t == idx) ? (0.9f * sim_idx + 0.1f * n2) * SCALE
                        : s_sims[t] * SCALE;
    const float mx = block_max16(sc, s_w, lane, wv);
    float e = (t < M_DIM) ? expf(sc - mx) : 0.f;
    const float esum = block_sum16(e, s_w, lane, wv);
    if (t < M_DIM) s_attn[t] = e / esum;

    // ---- phase 5: dkl_write = 0.5*||x - mem[idx]||^2, stash d in LDS ----
    float dwp = 0.f;
    if (t < C4) {
        float4 sl = mem4[(size_t)idx * C4 + t];
        float4 d;
        d.x = xt.x - sl.x; d.y = xt.y - sl.y; d.z = xt.z - sl.z; d.w = xt.w - sl.w;
        s_d4[t] = d;
        dwp = d.x * d.x + d.y * d.y + d.z * d.z + d.w * d.w;
    }
    const float dw = block_sum16(dwp, s_w, lane, wv);  // barrier publishes s_attn, s_d4

    // ---- phase 6: stream updated_memory + z partials (4 groups x 64 rows) ----
    const int tc = t & 255;              // column chunk (float4 id)
    const int mq = t >> 8;               // 0..3
    const int mbase = mq << 6;           // 0,64,128,192
    const float4 xc = s_x4[tc];
    float4 z = make_float4(0.f, 0.f, 0.f, 0.f);
    nfloat4* um4 = (nfloat4*)((float4*)(out + UM_OFF) + (size_t)b * M_DIM * C4 + tc);
    #pragma unroll 4
    for (int i = 0; i < 64; ++i) {
        const int m = mbase + i;
        float4 v = mem4[(size_t)m * C4 + tc];
        const float a = s_attn[m];
        // z from RAW mem row; idx-row correction applied analytically later
        z.x = fmaf(a, v.x, z.x);
        z.y = fmaf(a, v.y, z.y);
        z.z = fmaf(a, v.z, z.z);
        z.w = fmaf(a, v.w, z.w);
        if (m == idx) {      // wave-uniform branch, taken once per block
            v.x = 0.9f * v.x + 0.1f * xc.x;
            v.y = 0.9f * v.y + 0.1f * xc.y;
            v.z = 0.9f * v.z + 0.1f * xc.z;
            v.w = 0.9f * v.w + 0.1f * xc.w;
        }
        nfloat4 nv = { v.x, v.y, v.z, v.w };
        __builtin_nontemporal_store(nv, um4 + (size_t)m * C4);
    }

    // ---- combine 4 z partials, correction, dkl_read ----
    if (mq) s_z4[mq - 1][tc] = z;
    __syncthreads();
    float drp = 0.f;
    if (t < 256) {
        float4 z1 = s_z4[0][tc], z2 = s_z4[1][tc], z3 = s_z4[2][tc];
        z.x += z1.x + z2.x + z3.x;
        z.y += z1.y + z2.y + z3.y;
        z.z += z1.z + z2.z + z3.z;
        z.w += z1.w + z2.w + z3.w;
        const float aidx = s_attn[idx] * 0.1f;
        float4 d = s_d4[tc];
        z.x = fmaf(aidx, d.x, z.x);
        z.y = fmaf(aidx, d.y, z.y);
        z.z = fmaf(aidx, d.z, z.z);
        z.w = fmaf(aidx, d.w, z.w);
        float d0 = z.x - xc.x, d1 = z.y - xc.y, d2 = z.z - xc.z, d3 = z.w - xc.w;
        drp = d0 * d0 + d1 * d1 + d2 * d2 + d3 * d3;
        ((float4*)(out + Z_OFF))[(size_t)b * C4 + tc] = z;
    }
    const float dr = block_sum16(drp, s_w, lane, wv);

    if (t == 0) out[KL_OFF + b] = 0.5f * (dw + dr);
}

extern "C" void kernel_launch(void* const* d_in, const int* in_sizes, int n_in,
                              void* d_out, int out_size, void* d_ws, size_t ws_size,
                              hipStream_t stream) {
    const float* x   = (const float*)d_in[0];   // input_encoded [B, C]
    const float* mem = (const float*)d_in[1];   // memory_mean  [M, C]
    float* out = (float*)d_out;

    tm_fused<<<dim3(B_DIM), dim3(1024), 0, stream>>>(x, mem, out);
}